// Round 1
// baseline (249.882 us; speedup 1.0000x reference)
//
#include <hip/hip_runtime.h>
#include <math.h>

#define LVL 16
#define TBL 65536
#define BATCH 8
#define NPIX 65536       // 256*256
#define SDIM 512
#define HPRIME 2654435761u

struct ResPack { int r[LVL]; };

// ---------------------------------------------------------------------------
// Kernel A: per-batch modulated weights.
//   style_i = s[b]·aw_i + ab_i          (96 dot products of length 512)
//   demod_o = rsqrt(sum_i (w_oi*style_i)^2 + 1e-8)
//   W_eff[o][i] = w_oi * style_i * demod_o
// Layout in weff (per b, stride 2144 floats): [0,1024) L0, [1024,2048) L1,
// [2048,2144) L2 (3x32).
// ---------------------------------------------------------------------------
__global__ __launch_bounds__(256) void modw_kernel(
    const float* __restrict__ s,
    const float* __restrict__ w0, const float* __restrict__ aw0, const float* __restrict__ ab0,
    const float* __restrict__ w1, const float* __restrict__ aw1, const float* __restrict__ ab1,
    const float* __restrict__ w2, const float* __restrict__ aw2, const float* __restrict__ ab2,
    float* __restrict__ weff)
{
    const int b = blockIdx.x;
    __shared__ float style[96];
    __shared__ float demod[67];
    const float* sb = s + b * SDIM;
    const int wave = threadIdx.x >> 6;
    const int lane = threadIdx.x & 63;

    // 96 style dots, one per wave at a time (4 waves)
    for (int v = wave; v < 96; v += 4) {
        const float* row; float bias;
        if (v < 32)      { row = aw0 + v * SDIM;        bias = ab0[v]; }
        else if (v < 64) { row = aw1 + (v - 32) * SDIM; bias = ab1[v - 32]; }
        else             { row = aw2 + (v - 64) * SDIM; bias = ab2[v - 64]; }
        float acc = 0.f;
        for (int k = lane; k < SDIM; k += 64) acc += sb[k] * row[k];
        #pragma unroll
        for (int off = 32; off >= 1; off >>= 1) acc += __shfl_xor(acc, off, 64);
        if (lane == 0) style[v] = acc + bias;
    }
    __syncthreads();

    // 67 demod values (32 + 32 + 3)
    if (threadIdx.x < 67) {
        const int o = threadIdx.x;
        const float* wrow; const float* st;
        if (o < 32)      { wrow = w0 + o * 32;        st = style; }
        else if (o < 64) { wrow = w1 + (o - 32) * 32; st = style + 32; }
        else             { wrow = w2 + (o - 64) * 32; st = style + 64; }
        float sum = 0.f;
        #pragma unroll
        for (int i = 0; i < 32; ++i) { float v = wrow[i] * st[i]; sum += v * v; }
        demod[o] = 1.0f / sqrtf(sum + 1e-8f);
    }
    __syncthreads();

    float* outp = weff + b * 2144;
    for (int idx = (int)threadIdx.x; idx < 2144; idx += 256) {
        float v;
        if (idx < 1024) {
            int o = idx >> 5, i = idx & 31;
            v = w0[idx] * style[i] * demod[o];
        } else if (idx < 2048) {
            int j = idx - 1024; int o = j >> 5, i = j & 31;
            v = w1[j] * style[32 + i] * demod[32 + o];
        } else {
            int j = idx - 2048; int o = j >> 5, i = j & 31;
            v = w2[j] * style[64 + i] * demod[64 + o];
        }
        outp[idx] = v;
    }
}

// ---------------------------------------------------------------------------
// Kernel B: fused hash-encode + 3-layer MLP per pixel.
// grid = (NPIX/256, B), block = 256. Consecutive lanes = consecutive x
// (row-major n = y*256+x) so hash gathers within a wave permute a small
// contiguous window of the table.
// ---------------------------------------------------------------------------
__global__ __launch_bounds__(256) void fused_kernel(
    const float* __restrict__ tables,   // [B, L, T, 2]
    const float* __restrict__ coords,   // [N, 2]
    const float* __restrict__ weff,     // [B, 2144]
    const float* __restrict__ b0, const float* __restrict__ b1, const float* __restrict__ b2,
    float* __restrict__ out,            // [B, 3, 256, 256]
    ResPack res)
{
    const int n = blockIdx.x * 256 + threadIdx.x;
    const int b = blockIdx.y;

    const float cx = coords[2 * n];
    const float cy = coords[2 * n + 1];
    const float* tb = tables + (size_t)b * (LVL * TBL * 2);

    float feat[32];
    #pragma unroll
    for (int l = 0; l < LVL; ++l) {
        const int R = res.r[l];
        const float rm1 = (float)(R - 1);
        const float px = cx * rm1, py = cy * rm1;
        const float fpx = floorf(px), fpy = floorf(py);
        const float fx = px - fpx, fy = py - fpy;
        unsigned x0 = (unsigned)fpx, y0 = (unsigned)fpy;
        const unsigned im = (unsigned)(R - 1);
        unsigned x1 = x0 + 1u; if (x1 > im) x1 = im;
        unsigned y1 = y0 + 1u; if (y1 > im) y1 = im;
        const unsigned hy0 = y0 * HPRIME, hy1 = y1 * HPRIME;
        const unsigned h00 = (x0 ^ hy0) & 0xFFFFu;
        const unsigned h10 = (x1 ^ hy0) & 0xFFFFu;
        const unsigned h01 = (x0 ^ hy1) & 0xFFFFu;
        const unsigned h11 = (x1 ^ hy1) & 0xFFFFu;
        const float2* tl = (const float2*)(tb + l * (TBL * 2));
        const float2 g00 = tl[h00];
        const float2 g10 = tl[h10];
        const float2 g01 = tl[h01];
        const float2 g11 = tl[h11];
        const float w00 = (1.f - fx) * (1.f - fy);
        const float w10 = fx * (1.f - fy);
        const float w01 = (1.f - fx) * fy;
        const float w11 = fx * fy;
        feat[2 * l]     = g00.x * w00 + g10.x * w10 + g01.x * w01 + g11.x * w11;
        feat[2 * l + 1] = g00.y * w00 + g10.y * w10 + g01.y * w01 + g11.y * w11;
    }

    const float* W0 = weff + b * 2144;
    const float* W1 = W0 + 1024;
    const float* W2 = W0 + 2048;

    float h1[32];
    #pragma unroll
    for (int o = 0; o < 32; ++o) {
        float acc = b0[o];
        #pragma unroll
        for (int i = 0; i < 32; ++i) acc = fmaf(W0[o * 32 + i], feat[i], acc);
        h1[o] = fmaxf(acc, 0.f);
    }

    float h2[32];
    #pragma unroll
    for (int o = 0; o < 32; ++o) {
        float acc = b1[o];
        #pragma unroll
        for (int i = 0; i < 32; ++i) acc = fmaf(W1[o * 32 + i], h1[i], acc);
        h2[o] = fmaxf(acc, 0.f);
    }

    #pragma unroll
    for (int o = 0; o < 3; ++o) {
        float acc = b2[o];
        #pragma unroll
        for (int i = 0; i < 32; ++i) acc = fmaf(W2[o * 32 + i], h2[i], acc);
        out[((size_t)(b * 3 + o) << 16) + n] = tanhf(acc);
    }
}

// ---------------------------------------------------------------------------
extern "C" void kernel_launch(void* const* d_in, const int* in_sizes, int n_in,
                              void* d_out, int out_size, void* d_ws, size_t ws_size,
                              hipStream_t stream) {
    const float* x      = (const float*)d_in[0];
    const float* s      = (const float*)d_in[1];
    const float* coords = (const float*)d_in[2];
    const float* w0  = (const float*)d_in[3];
    const float* aw0 = (const float*)d_in[4];
    const float* ab0 = (const float*)d_in[5];
    const float* b0  = (const float*)d_in[6];
    const float* w1  = (const float*)d_in[7];
    const float* aw1 = (const float*)d_in[8];
    const float* ab1 = (const float*)d_in[9];
    const float* b1  = (const float*)d_in[10];
    const float* w2  = (const float*)d_in[11];
    const float* aw2 = (const float*)d_in[12];
    const float* ab2 = (const float*)d_in[13];
    const float* b2  = (const float*)d_in[14];
    float* out  = (float*)d_out;
    float* weff = (float*)d_ws;   // 8 * 2144 floats = 68608 B

    // Resolution levels, matching np.round(RES_MIN * b**l) in double precision.
    ResPack rp;
    const double g = pow(256.0 / 16.0, 1.0 / 15.0);
    for (int l = 0; l < LVL; ++l) {
        double r = 16.0 * pow(g, (double)l);
        long ri = lround(r);
        if (ri > 256) ri = 256;
        rp.r[l] = (int)ri;
    }

    hipLaunchKernelGGL(modw_kernel, dim3(BATCH), dim3(256), 0, stream,
                       s, w0, aw0, ab0, w1, aw1, ab1, w2, aw2, ab2, weff);
    hipLaunchKernelGGL(fused_kernel, dim3(NPIX / 256, BATCH), dim3(256), 0, stream,
                       x, coords, weff, b0, b1, b2, out, rp);
}

// Round 5
// 234.705 us; speedup vs baseline: 1.0647x; 1.0647x over previous
//
#include <hip/hip_runtime.h>
#include <math.h>

#define LVL 16
#define TBL 65536
#define BATCH 8
#define NPIX 65536       // 256*256
#define SDIM 512
#define HPRIME 2654435761u

typedef __attribute__((ext_vector_type(2))) float f32x2;

struct ResPack { int r[LVL]; };

static __device__ __forceinline__ f32x2 splat2(float v) { f32x2 r = {v, v}; return r; }
static __device__ __forceinline__ f32x2 vmax0(f32x2 v) {
    f32x2 r; r[0] = fmaxf(v[0], 0.f); r[1] = fmaxf(v[1], 0.f); return r;
}

// ---------------------------------------------------------------------------
// Kernel A (round-1 verified, unchanged): fp32 modulated weights.
// weff per b (stride 2144 floats): [0,1024) W0 [32][32] (o,i), [1024,2048) W1,
// [2048,2144) W2 [3][32].
// ---------------------------------------------------------------------------
__global__ __launch_bounds__(256) void modw_kernel(
    const float* __restrict__ s,
    const float* __restrict__ w0, const float* __restrict__ aw0, const float* __restrict__ ab0,
    const float* __restrict__ w1, const float* __restrict__ aw1, const float* __restrict__ ab1,
    const float* __restrict__ w2, const float* __restrict__ aw2, const float* __restrict__ ab2,
    float* __restrict__ weff)
{
    const int b = blockIdx.x;
    __shared__ float style[96];
    __shared__ float demod[67];
    const float* sb = s + b * SDIM;
    const int wave = threadIdx.x >> 6;
    const int lane = threadIdx.x & 63;

    for (int v = wave; v < 96; v += 4) {
        const float* row; float bias;
        if (v < 32)      { row = aw0 + v * SDIM;        bias = ab0[v]; }
        else if (v < 64) { row = aw1 + (v - 32) * SDIM; bias = ab1[v - 32]; }
        else             { row = aw2 + (v - 64) * SDIM; bias = ab2[v - 64]; }
        float acc = 0.f;
        for (int k = lane; k < SDIM; k += 64) acc += sb[k] * row[k];
        #pragma unroll
        for (int off = 32; off >= 1; off >>= 1) acc += __shfl_xor(acc, off, 64);
        if (lane == 0) style[v] = acc + bias;
    }
    __syncthreads();

    if (threadIdx.x < 67) {
        const int o = threadIdx.x;
        const float* wrow; const float* st;
        if (o < 32)      { wrow = w0 + o * 32;        st = style; }
        else if (o < 64) { wrow = w1 + (o - 32) * 32; st = style + 32; }
        else             { wrow = w2 + (o - 64) * 32; st = style + 64; }
        float sum = 0.f;
        #pragma unroll
        for (int i = 0; i < 32; ++i) { float v = wrow[i] * st[i]; sum += v * v; }
        demod[o] = 1.0f / sqrtf(sum + 1e-8f);
    }
    __syncthreads();

    float* outp = weff + b * 2144;
    for (int idx = (int)threadIdx.x; idx < 2144; idx += 256) {
        float v;
        if (idx < 1024) {
            int o = idx >> 5, i = idx & 31;
            v = w0[idx] * style[i] * demod[o];
        } else if (idx < 2048) {
            int j = idx - 1024; int o = j >> 5, i = j & 31;
            v = w1[j] * style[32 + i] * demod[32 + o];
        } else {
            int j = idx - 2048; int o = j >> 5, i = j & 31;
            v = w2[j] * style[64 + i] * demod[64 + o];
        }
        outp[idx] = v;
    }
}

// ---------------------------------------------------------------------------
// Kernel B: scalar fp32 (round-1 verified math), PX=2 pixels/thread with
// float2 packed arithmetic (v_pk_fma_f32 path) + batched hash gathers
// (8 levels x 4 corners clustered before interpolation).
// grid = (NPIX/512, B), block = 256. Thread t: pixels base+t and base+t+256.
// ---------------------------------------------------------------------------
__global__ __launch_bounds__(256, 2) void fused_kernel(
    const float* __restrict__ tables,   // [B, L, T, 2]
    const float* __restrict__ coords,   // [N, 2]
    const float* __restrict__ weff,     // [B, 2144] fp32
    const float* __restrict__ b0, const float* __restrict__ b1, const float* __restrict__ b2,
    float* __restrict__ out,            // [B, 3, 256, 256]
    ResPack res)
{
    const int tid = (int)threadIdx.x;
    const int b   = blockIdx.y;
    const int n0  = blockIdx.x * 512 + tid;
    const int n1  = n0 + 256;

    const float* tb = tables + (size_t)b * (LVL * TBL * 2);

    f32x2 feat[32];

    #pragma unroll
    for (int px = 0; px < 2; ++px) {
        const int n = px ? n1 : n0;
        const float cx = coords[2 * n];
        const float cy = coords[2 * n + 1];

        #pragma unroll
        for (int half = 0; half < 2; ++half) {
            float2 g[8][4];
            float fxs[8], fys[8];

            // Phase 1: compute indices + issue all 32 gathers (clustered).
            #pragma unroll
            for (int j = 0; j < 8; ++j) {
                const int l = half * 8 + j;
                const int R = res.r[l];
                const float rm1 = (float)(R - 1);
                const float px_ = cx * rm1, py_ = cy * rm1;
                const float fpx = floorf(px_), fpy = floorf(py_);
                fxs[j] = px_ - fpx; fys[j] = py_ - fpy;
                unsigned x0 = (unsigned)fpx, y0 = (unsigned)fpy;
                const unsigned im = (unsigned)(R - 1);
                unsigned x1 = x0 + 1u; if (x1 > im) x1 = im;
                unsigned y1 = y0 + 1u; if (y1 > im) y1 = im;
                const unsigned hy0 = y0 * HPRIME, hy1 = y1 * HPRIME;
                const unsigned h00 = (x0 ^ hy0) & 0xFFFFu;
                const unsigned h10 = (x1 ^ hy0) & 0xFFFFu;
                const unsigned h01 = (x0 ^ hy1) & 0xFFFFu;
                const unsigned h11 = (x1 ^ hy1) & 0xFFFFu;
                const float2* tl = (const float2*)(tb + l * (TBL * 2));
                g[j][0] = tl[h00];
                g[j][1] = tl[h10];
                g[j][2] = tl[h01];
                g[j][3] = tl[h11];
            }

            // Phase 2: interpolate.
            #pragma unroll
            for (int j = 0; j < 8; ++j) {
                const int l = half * 8 + j;
                const float fx = fxs[j], fy = fys[j];
                const float w00 = (1.f - fx) * (1.f - fy);
                const float w10 = fx * (1.f - fy);
                const float w01 = (1.f - fx) * fy;
                const float w11 = fx * fy;
                const float f0 = g[j][0].x * w00 + g[j][1].x * w10 + g[j][2].x * w01 + g[j][3].x * w11;
                const float f1 = g[j][0].y * w00 + g[j][1].y * w10 + g[j][2].y * w01 + g[j][3].y * w11;
                feat[2 * l][px]     = f0;
                feat[2 * l + 1][px] = f1;
            }
        }
    }

    // ---- MLP: packed fp32, weights uniform (scalar-fed) --------------------
    const float* W0 = weff + (size_t)b * 2144;
    const float* W1 = W0 + 1024;
    const float* W2 = W0 + 2048;

    f32x2 h1[32];
    #pragma unroll
    for (int o = 0; o < 32; ++o) {
        f32x2 acc = splat2(b0[o]);
        #pragma unroll
        for (int i = 0; i < 32; ++i) acc += W0[o * 32 + i] * feat[i];
        h1[o] = vmax0(acc);
    }

    f32x2 h2[32];
    #pragma unroll
    for (int o = 0; o < 32; ++o) {
        f32x2 acc = splat2(b1[o]);
        #pragma unroll
        for (int i = 0; i < 32; ++i) acc += W1[o * 32 + i] * h1[i];
        h2[o] = vmax0(acc);
    }

    #pragma unroll
    for (int o = 0; o < 3; ++o) {
        f32x2 acc = splat2(b2[o]);
        #pragma unroll
        for (int i = 0; i < 32; ++i) acc += W2[o * 32 + i] * h2[i];
        float* op = out + (((size_t)(b * 3 + o)) << 16);
        op[n0] = tanhf(acc[0]);
        op[n1] = tanhf(acc[1]);
    }
}

// ---------------------------------------------------------------------------
extern "C" void kernel_launch(void* const* d_in, const int* in_sizes, int n_in,
                              void* d_out, int out_size, void* d_ws, size_t ws_size,
                              hipStream_t stream) {
    const float* x      = (const float*)d_in[0];
    const float* s      = (const float*)d_in[1];
    const float* coords = (const float*)d_in[2];
    const float* w0  = (const float*)d_in[3];
    const float* aw0 = (const float*)d_in[4];
    const float* ab0 = (const float*)d_in[5];
    const float* b0  = (const float*)d_in[6];
    const float* w1  = (const float*)d_in[7];
    const float* aw1 = (const float*)d_in[8];
    const float* ab1 = (const float*)d_in[9];
    const float* b1  = (const float*)d_in[10];
    const float* w2  = (const float*)d_in[11];
    const float* aw2 = (const float*)d_in[12];
    const float* ab2 = (const float*)d_in[13];
    const float* b2  = (const float*)d_in[14];
    float* out  = (float*)d_out;
    float* weff = (float*)d_ws;   // 8 * 2144 floats = 68608 B

    ResPack rp;
    const double g = pow(256.0 / 16.0, 1.0 / 15.0);
    for (int l = 0; l < LVL; ++l) {
        double r = 16.0 * pow(g, (double)l);
        long ri = lround(r);
        if (ri > 256) ri = 256;
        rp.r[l] = (int)ri;
    }

    hipLaunchKernelGGL(modw_kernel, dim3(BATCH), dim3(256), 0, stream,
                       s, w0, aw0, ab0, w1, aw1, ab1, w2, aw2, ab2, weff);
    hipLaunchKernelGGL(fused_kernel, dim3(NPIX / 512, BATCH), dim3(256), 0, stream,
                       x, coords, weff, b0, b1, b2, out, rp);
}